// Round 7
// baseline (362.769 us; speedup 1.0000x reference)
//
#include <hip/hip_runtime.h>
#include <stdint.h>

typedef unsigned short ushort_t;
typedef __attribute__((ext_vector_type(8))) short short8;
typedef __attribute__((ext_vector_type(4))) unsigned short ushort4_t;
typedef __attribute__((ext_vector_type(8))) unsigned short ushort8;
typedef __attribute__((ext_vector_type(4))) float f32x4;

#define TOK 8192
#define DIM_IN 4096
#define DIM_OUT 4096
#define RANK 64
#define NT32 (DIM_IN / 32)   // 128 K-tiles of BK=32

// fp32 -> bf16 round-to-nearest-even
__device__ __forceinline__ ushort_t f2bf(float f) {
    unsigned u = __float_as_uint(f);
    unsigned r = (u + 0x7fffu + ((u >> 16) & 1u)) >> 16;
    return (ushort_t)r;
}
__device__ __forceinline__ float bf2f(ushort_t u) {
    return __uint_as_float(((unsigned)u) << 16);
}

__device__ __forceinline__ void gload16(const void* g, void* l) {
    __builtin_amdgcn_global_load_lds(
        (const __attribute__((address_space(1))) unsigned int*)g,
        (__attribute__((address_space(3))) unsigned int*)l,
        16, 0, 0);
}

// ---------------- Kernel 1: input fp32 -> bf16 ----------------
__global__ __launch_bounds__(256) void prep_input_k(const float* __restrict__ in,
                                                    ushort_t* __restrict__ out) {
    size_t idx = (size_t)blockIdx.x * 256 + threadIdx.x;
    const float4* p = (const float4*)(in + idx * 8);
    float4 f0 = p[0], f1 = p[1];
    ushort8 o;
    o[0] = f2bf(f0.x); o[1] = f2bf(f0.y); o[2] = f2bf(f0.z); o[3] = f2bf(f0.w);
    o[4] = f2bf(f1.x); o[5] = f2bf(f1.y); o[6] = f2bf(f1.z); o[7] = f2bf(f1.w);
    *(ushort8*)(out + idx * 8) = o;
}

// ---------------- Kernel 2: W_eff = dequant(Wq,scale) + U*diag(s)*V^T -> bf16 ----------------
// MFMA version (r6 proven): svd part via bf16 16x16x32 MFMA per 128x128 tile,
// rounded to bf16 through LDS, then coalesced merge with dequantized wq.
__global__ __launch_bounds__(256) void prep_weight_k(const float* __restrict__ wq,
                                                     const float* __restrict__ scale,
                                                     const float* __restrict__ U,
                                                     const float* __restrict__ s,
                                                     const float* __restrict__ V,
                                                     ushort_t* __restrict__ Wb) {
    __shared__ ushort_t sm[18432];   // 36 KiB
    const int tid = threadIdx.x;
    const int wv = tid >> 6;
    const int lane = tid & 63;
    const int ob = blockIdx.x >> 5;
    const int kb = blockIdx.x & 31;

    // ---- stage U' = U*s and V' = V as bf16, swizzled (byte ^= (row&7)<<4)
    char* smb = (char*)sm;
#pragma unroll
    for (int j = 0; j < 8; ++j) {
        int idx = j * 256 + tid;          // 0..2047 float4 slots
        int row = idx >> 4;               // 0..127
        int c4 = idx & 15;                // float4 col index (cols c4*4)
        float4 sv = *(const float4*)&s[c4 * 4];
        float4 u = *(const float4*)&U[(size_t)(ob * 128 + row) * RANK + c4 * 4];
        ushort4_t up;
        up[0] = f2bf(u.x * sv.x); up[1] = f2bf(u.y * sv.y);
        up[2] = f2bf(u.z * sv.z); up[3] = f2bf(u.w * sv.w);
        int wbyte = row * 128 + ((c4 * 8) ^ ((row & 7) << 4));
        *(ushort4_t*)(smb + wbyte) = up;
        float4 v = *(const float4*)&V[(size_t)(kb * 128 + row) * RANK + c4 * 4];
        ushort4_t vp;
        vp[0] = f2bf(v.x); vp[1] = f2bf(v.y); vp[2] = f2bf(v.z); vp[3] = f2bf(v.w);
        *(ushort4_t*)(smb + 16384 + wbyte) = vp;
    }
    __syncthreads();

    // ---- MFMA: wave wv -> out quadrant (wr = wv>>1)*64 rows, (wc = wv&1)*64 cols
    const int wr = wv >> 1, wc = wv & 1;
    f32x4 acc[4][4] = {};
    {
        short8 a[4], b[4];
#pragma unroll
        for (int kk = 0; kk < 2; ++kk) {
#pragma unroll
            for (int f = 0; f < 4; ++f) {
                int r = wr * 64 + f * 16 + (lane & 15);
                int kbyte = ((lane >> 4) * 16 + kk * 64) ^ ((r & 7) << 4);
                a[f] = *(const short8*)(smb + r * 128 + kbyte);
                int r2 = wc * 64 + f * 16 + (lane & 15);
                int kbyte2 = ((lane >> 4) * 16 + kk * 64) ^ ((r2 & 7) << 4);
                b[f] = *(const short8*)(smb + 16384 + r2 * 128 + kbyte2);
            }
#pragma unroll
            for (int fm = 0; fm < 4; ++fm)
#pragma unroll
                for (int fn = 0; fn < 4; ++fn)
                    acc[fm][fn] = __builtin_amdgcn_mfma_f32_16x16x32_bf16(
                        a[fm], b[fn], acc[fm][fn], 0, 0, 0);
        }
    }
    __syncthreads();   // all MFMA reads of U'/V' done before overwrite

    // ---- spill svd (bf16) to LDS as [128][136] ushort
#pragma unroll
    for (int fm = 0; fm < 4; ++fm)
#pragma unroll
        for (int fn = 0; fn < 4; ++fn) {
            int row0 = wr * 64 + fm * 16 + (lane >> 4) * 4;
            int col = wc * 64 + fn * 16 + (lane & 15);
#pragma unroll
            for (int r = 0; r < 4; ++r)
                sm[(row0 + r) * 136 + col] = f2bf(acc[fm][fn][r]);
        }
    __syncthreads();

    // ---- merge: out = wq*scale + svd, coalesced ushort8 stores
    const int ty = tid >> 4, tx = tid & 15;
#pragma unroll
    for (int i = 0; i < 8; ++i) {
        int ol = ty * 8 + i;
        int o = ob * 128 + ol;
        int k0 = kb * 128 + tx * 8;
        float sc = scale[(size_t)o * (DIM_IN / 32) + (k0 >> 5)];
        float4 q0 = *(const float4*)&wq[(size_t)o * DIM_IN + k0];
        float4 q1 = *(const float4*)&wq[(size_t)o * DIM_IN + k0 + 4];
        ushort8 sv8 = *(const ushort8*)&sm[ol * 136 + tx * 8];
        ushort8 w;
        w[0] = f2bf(q0.x * sc + bf2f(sv8[0]));
        w[1] = f2bf(q0.y * sc + bf2f(sv8[1]));
        w[2] = f2bf(q0.z * sc + bf2f(sv8[2]));
        w[3] = f2bf(q0.w * sc + bf2f(sv8[3]));
        w[4] = f2bf(q1.x * sc + bf2f(sv8[4]));
        w[5] = f2bf(q1.y * sc + bf2f(sv8[5]));
        w[6] = f2bf(q1.z * sc + bf2f(sv8[6]));
        w[7] = f2bf(q1.w * sc + bf2f(sv8[7]));
        *(ushort8*)&Wb[(size_t)o * DIM_IN + k0] = w;
    }
}

// ---------------- Kernel 3: 256x128-tile GEMM, 2 blocks/CU, C = A @ B^T + bias ----
// 256 threads (4 waves, 2M x 2N), wave tile 128x64 (optimal LDS B/FLOP), BK=32,
// classic double-buffer 2-phase: {stage(next) || 12 ds_reads || 32 MFMA} ->
// vmcnt(0) -> barrier. LDS 48 KiB -> 2 independent blocks co-resident per CU:
// one block's MFMA/ds_reads fill the other's stage/barrier stalls (m97
// implicit wave-level overlap) instead of manual pipelining.
// LDS layout per buf: A = 16 subtiles [16 rows x 32 k] of 1024B, B = 8 subtiles;
// st_16x32 swizzle via pre-swizzled global source (lane2) + swizzled read (loff)
// -- identical formulas to the proven r4 kernel, re-verified lane-by-lane.
__global__ __launch_bounds__(256, 2) void gemm_k(const ushort_t* __restrict__ A,
                                                 const ushort_t* __restrict__ B,
                                                 const float* __restrict__ bias,
                                                 float* __restrict__ C) {
    __shared__ ushort_t lds[2][12288];   // per buf: A 8192 elems | B 4096 elems

    const int tid = threadIdx.x;
    const int wid = tid >> 6;      // 0..3
    const int lane = tid & 63;

    // XCD-aware bijective swizzle: 1024 blocks, 8 XCDs, 128 per XCD
    int bid = blockIdx.x;
    int swz = (bid & 7) * 128 + (bid >> 3);
    const int bm = swz >> 5;       // 32 M-tiles (256 rows)
    const int bn = swz & 31;       // 32 N-tiles (128 cols)

    const int wr = wid >> 1;       // 0..1 (M half, 128 rows)
    const int wc = wid & 1;        // 0..1 (N half, 64 cols)

    // --- staging source (pre-swizzled; inverse of st_16x32)
    const int lane2 = lane ^ (((lane >> 5) & 1) << 1);
    const int sr = lane2 >> 2;            // 0..15 row within subtile
    const int sc = (lane2 & 3) * 8;       // k-col within 32-k block
    const ushort_t* pa = A + (size_t)(bm * 256 + sr) * DIM_IN + sc;
    const ushort_t* pb = B + (size_t)(bn * 128 + sr) * DIM_IN + sc;

    // --- swizzled per-lane ds_read offset within a [16x32] subtile (elem units)
    const int loff = ((((lane & 15) * 64 + (lane >> 4) * 16) ^ (((lane >> 3) & 1) << 5)) >> 1);

    f32x4 acc[8][4] = {};

    // stage tile t into lds[buf]: wave wid -> A subtiles wid*4..+3, B subtiles wid*2..+1
    auto stage = [&](int buf, int t) {
#pragma unroll
        for (int j = 0; j < 4; ++j) {
            int s = wid * 4 + j;
            gload16(pa + (size_t)(s * 16) * DIM_IN + t * 32, &lds[buf][s * 512]);
        }
#pragma unroll
        for (int j = 0; j < 2; ++j) {
            int s = wid * 2 + j;
            gload16(pb + (size_t)(s * 16) * DIM_IN + t * 32, &lds[buf][8192 + s * 512]);
        }
    };

    stage(0, 0);
    asm volatile("s_waitcnt vmcnt(0)" ::: "memory");
    __builtin_amdgcn_s_barrier();

    for (int t = 0; t < NT32; ++t) {
        const int cur = t & 1;
        if (t + 1 < NT32) stage(cur ^ 1, t + 1);

        const ushort_t* L = &lds[cur][0];
        short8 a[8], b[4];
#pragma unroll
        for (int m = 0; m < 8; ++m)
            a[m] = *(const short8*)(L + (wr * 8 + m) * 512 + loff);
#pragma unroll
        for (int n = 0; n < 4; ++n)
            b[n] = *(const short8*)(L + 8192 + (wc * 4 + n) * 512 + loff);

        __builtin_amdgcn_s_setprio(1);
#pragma unroll
        for (int m = 0; m < 8; ++m)
#pragma unroll
            for (int n = 0; n < 4; ++n)
                acc[m][n] = __builtin_amdgcn_mfma_f32_16x16x32_bf16(a[m], b[n], acc[m][n], 0, 0, 0);
        __builtin_amdgcn_s_setprio(0);

        if (t + 1 < NT32) {
            asm volatile("s_waitcnt vmcnt(0)" ::: "memory");
            __builtin_amdgcn_s_barrier();
        }
    }

    // ---- epilogue: C/D layout col = lane&15, row = (lane>>4)*4 + reg
    const int ccol = lane & 15;
    const int crow = (lane >> 4) * 4;
#pragma unroll
    for (int n = 0; n < 4; ++n) {
        int gcol = bn * 128 + wc * 64 + n * 16 + ccol;
        float bv = bias[gcol];
#pragma unroll
        for (int m = 0; m < 8; ++m) {
            size_t grow = (size_t)(bm * 256 + wr * 128 + m * 16 + crow);
#pragma unroll
            for (int r = 0; r < 4; ++r)
                C[(grow + r) * DIM_OUT + gcol] = acc[m][n][r] + bv;
        }
    }
}

extern "C" void kernel_launch(void* const* d_in, const int* in_sizes, int n_in,
                              void* d_out, int out_size, void* d_ws, size_t ws_size,
                              hipStream_t stream) {
    const float* input = (const float*)d_in[0];
    const float* wq    = (const float*)d_in[1];
    const float* scale = (const float*)d_in[2];
    const float* bias  = (const float*)d_in[3];
    const float* U     = (const float*)d_in[4];
    const float* s     = (const float*)d_in[5];
    const float* V     = (const float*)d_in[6];
    float* out = (float*)d_out;

    ushort_t* Abf = (ushort_t*)d_ws;                       // 8192*4096*2 = 64 MB
    ushort_t* Wbf = Abf + (size_t)TOK * DIM_IN;            // 4096*4096*2 = 32 MB

    prep_input_k<<<(TOK * DIM_IN) / (256 * 8), 256, 0, stream>>>(input, Abf);
    prep_weight_k<<<(DIM_OUT / 128) * (DIM_IN / 128), 256, 0, stream>>>(wq, scale, U, s, V, Wbf);
    gemm_k<<<(TOK / 256) * (DIM_OUT / 128), 256, 0, stream>>>(Abf, Wbf, bias, out);
}

// Round 8
// 335.252 us; speedup vs baseline: 1.0821x; 1.0821x over previous
//
#include <hip/hip_runtime.h>
#include <stdint.h>

typedef unsigned short ushort_t;
typedef __attribute__((ext_vector_type(8))) short short8;
typedef __attribute__((ext_vector_type(4))) unsigned short ushort4_t;
typedef __attribute__((ext_vector_type(8))) unsigned short ushort8;
typedef __attribute__((ext_vector_type(4))) float f32x4;

#define TOK 8192
#define DIM_IN 4096
#define DIM_OUT 4096
#define RANK 64
#define NT (DIM_IN / 64)   // 64 K-tiles of BK=64

// fp32 -> bf16 round-to-nearest-even
__device__ __forceinline__ ushort_t f2bf(float f) {
    unsigned u = __float_as_uint(f);
    unsigned r = (u + 0x7fffu + ((u >> 16) & 1u)) >> 16;
    return (ushort_t)r;
}
__device__ __forceinline__ float bf2f(ushort_t u) {
    return __uint_as_float(((unsigned)u) << 16);
}

__device__ __forceinline__ void gload16(const void* g, void* l) {
    __builtin_amdgcn_global_load_lds(
        (const __attribute__((address_space(1))) unsigned int*)g,
        (__attribute__((address_space(3))) unsigned int*)l,
        16, 0, 0);
}

// ---------------- Kernel 1: input fp32 -> bf16 ----------------
__global__ __launch_bounds__(256) void prep_input_k(const float* __restrict__ in,
                                                    ushort_t* __restrict__ out) {
    size_t idx = (size_t)blockIdx.x * 256 + threadIdx.x;
    const float4* p = (const float4*)(in + idx * 8);
    float4 f0 = p[0], f1 = p[1];
    ushort8 o;
    o[0] = f2bf(f0.x); o[1] = f2bf(f0.y); o[2] = f2bf(f0.z); o[3] = f2bf(f0.w);
    o[4] = f2bf(f1.x); o[5] = f2bf(f1.y); o[6] = f2bf(f1.z); o[7] = f2bf(f1.w);
    *(ushort8*)(out + idx * 8) = o;
}

// ---------------- Kernel 2: W_eff = dequant(Wq,scale) + U*diag(s)*V^T -> bf16 ----------------
// MFMA version (r6 proven): svd part via bf16 16x16x32 MFMA per 128x128 tile,
// rounded to bf16 through LDS, then coalesced merge with dequantized wq.
__global__ __launch_bounds__(256) void prep_weight_k(const float* __restrict__ wq,
                                                     const float* __restrict__ scale,
                                                     const float* __restrict__ U,
                                                     const float* __restrict__ s,
                                                     const float* __restrict__ V,
                                                     ushort_t* __restrict__ Wb) {
    __shared__ ushort_t sm[18432];   // 36 KiB
    const int tid = threadIdx.x;
    const int wv = tid >> 6;
    const int lane = tid & 63;
    const int ob = blockIdx.x >> 5;
    const int kb = blockIdx.x & 31;

    // ---- stage U' = U*s and V' = V as bf16, swizzled (byte ^= (row&7)<<4)
    char* smb = (char*)sm;
#pragma unroll
    for (int j = 0; j < 8; ++j) {
        int idx = j * 256 + tid;          // 0..2047 float4 slots
        int row = idx >> 4;               // 0..127
        int c4 = idx & 15;                // float4 col index (cols c4*4)
        float4 sv = *(const float4*)&s[c4 * 4];
        float4 u = *(const float4*)&U[(size_t)(ob * 128 + row) * RANK + c4 * 4];
        ushort4_t up;
        up[0] = f2bf(u.x * sv.x); up[1] = f2bf(u.y * sv.y);
        up[2] = f2bf(u.z * sv.z); up[3] = f2bf(u.w * sv.w);
        int wbyte = row * 128 + ((c4 * 8) ^ ((row & 7) << 4));
        *(ushort4_t*)(smb + wbyte) = up;
        float4 v = *(const float4*)&V[(size_t)(kb * 128 + row) * RANK + c4 * 4];
        ushort4_t vp;
        vp[0] = f2bf(v.x); vp[1] = f2bf(v.y); vp[2] = f2bf(v.z); vp[3] = f2bf(v.w);
        *(ushort4_t*)(smb + 16384 + wbyte) = vp;
    }
    __syncthreads();

    // ---- MFMA: wave wv -> out quadrant (wr = wv>>1)*64 rows, (wc = wv&1)*64 cols
    const int wr = wv >> 1, wc = wv & 1;
    f32x4 acc[4][4] = {};
    {
        short8 a[4], b[4];
#pragma unroll
        for (int kk = 0; kk < 2; ++kk) {
#pragma unroll
            for (int f = 0; f < 4; ++f) {
                int r = wr * 64 + f * 16 + (lane & 15);
                int kbyte = ((lane >> 4) * 16 + kk * 64) ^ ((r & 7) << 4);
                a[f] = *(const short8*)(smb + r * 128 + kbyte);
                int r2 = wc * 64 + f * 16 + (lane & 15);
                int kbyte2 = ((lane >> 4) * 16 + kk * 64) ^ ((r2 & 7) << 4);
                b[f] = *(const short8*)(smb + 16384 + r2 * 128 + kbyte2);
            }
#pragma unroll
            for (int fm = 0; fm < 4; ++fm)
#pragma unroll
                for (int fn = 0; fn < 4; ++fn)
                    acc[fm][fn] = __builtin_amdgcn_mfma_f32_16x16x32_bf16(
                        a[fm], b[fn], acc[fm][fn], 0, 0, 0);
        }
    }
    __syncthreads();   // all MFMA reads of U'/V' done before overwrite

    // ---- spill svd (bf16) to LDS as [128][136] ushort
#pragma unroll
    for (int fm = 0; fm < 4; ++fm)
#pragma unroll
        for (int fn = 0; fn < 4; ++fn) {
            int row0 = wr * 64 + fm * 16 + (lane >> 4) * 4;
            int col = wc * 64 + fn * 16 + (lane & 15);
#pragma unroll
            for (int r = 0; r < 4; ++r)
                sm[(row0 + r) * 136 + col] = f2bf(acc[fm][fn][r]);
        }
    __syncthreads();

    // ---- merge: out = wq*scale + svd, coalesced ushort8 stores
    const int ty = tid >> 4, tx = tid & 15;
#pragma unroll
    for (int i = 0; i < 8; ++i) {
        int ol = ty * 8 + i;
        int o = ob * 128 + ol;
        int k0 = kb * 128 + tx * 8;
        float sc = scale[(size_t)o * (DIM_IN / 32) + (k0 >> 5)];
        float4 q0 = *(const float4*)&wq[(size_t)o * DIM_IN + k0];
        float4 q1 = *(const float4*)&wq[(size_t)o * DIM_IN + k0 + 4];
        ushort8 sv8 = *(const ushort8*)&sm[ol * 136 + tx * 8];
        ushort8 w;
        w[0] = f2bf(q0.x * sc + bf2f(sv8[0]));
        w[1] = f2bf(q0.y * sc + bf2f(sv8[1]));
        w[2] = f2bf(q0.z * sc + bf2f(sv8[2]));
        w[3] = f2bf(q0.w * sc + bf2f(sv8[3]));
        w[4] = f2bf(q1.x * sc + bf2f(sv8[4]));
        w[5] = f2bf(q1.y * sc + bf2f(sv8[5]));
        w[6] = f2bf(q1.z * sc + bf2f(sv8[6]));
        w[7] = f2bf(q1.w * sc + bf2f(sv8[7]));
        *(ushort8*)&Wb[(size_t)o * DIM_IN + k0] = w;
    }
}

// ---------------- Kernel 3: 256^2 GEMM, burst-staged, C = A @ B^T + bias ----------------
// 512 threads (8 waves, 2M x 4N), BK=64, st_16x32-swizzled LDS, acc 8x4 f32x4.
// Per tile: [consume cur: 24 ds_reads one-segment-ahead + 64 MFMA, NO barriers]
// -> barrier (all waves drained their reads via MFMA data deps)
// -> burst stage(cur <- t+2, 8 gloads) -> vmcnt(8) (t+1's 8 loads landed)
// -> barrier -> consume cur^1. Only 2 barriers + 1 counted vmcnt per tile; the
// barrier-free 2483-cyc MFMA stretch lets drifted waves fill each other's LDS
// pipe gaps (the overlap r7 failed to get from co-resident blocks).
__global__ __launch_bounds__(512, 2) void gemm_k(const ushort_t* __restrict__ A,
                                                 const ushort_t* __restrict__ B,
                                                 const float* __restrict__ bias,
                                                 float* __restrict__ C) {
    __shared__ ushort_t lds[2][2][2][8192];

    const int tid = threadIdx.x;
    const int wid = tid >> 6;
    const int lane = tid & 63;

    // XCD-aware bijective swizzle: 512 blocks, 8 XCDs, 64 per XCD
    int bid = blockIdx.x;
    int swz = (bid & 7) * 64 + (bid >> 3);
    const int bm = swz >> 4;   // 32 M-tiles
    const int bn = swz & 15;   // 16 N-tiles

    const int wr = wid >> 2;   // 0..1 (M)
    const int wc = wid & 3;    // 0..3 (N)

    // --- staging: wave wid fills subtiles {wid, wid+8} of each 128x64 half-tile.
    const int lane2 = lane ^ (((lane >> 5) & 1) << 1);
    const int srow = (wid >> 1) * 16 + (lane2 >> 2);
    const int scol = (wid & 1) * 32 + (lane2 & 3) * 8;
    const ushort_t* pa = A + (size_t)(bm * 256 + srow) * DIM_IN + scol;
    const ushort_t* pb = B + (size_t)(bn * 256 + srow) * DIM_IN + scol;

    // --- swizzled per-lane ds_read offset (element units)
    const int loff = ((((lane & 15) * 64 + (lane >> 4) * 16) ^ (((lane >> 3) & 1) << 5)) >> 1);

    f32x4 acc[8][4] = {};

    // stage full K-tile t into buf: A halves 0,1 + B halves 0,1 (8 gloads)
    auto stage = [&](int buf, int t) {
#pragma unroll
        for (int half = 0; half < 2; ++half) {
            const ushort_t* ga = pa + (size_t)half * 128 * DIM_IN + t * 64;
            gload16(ga, &lds[buf][0][half][wid * 512]);
            gload16(ga + (size_t)64 * DIM_IN, &lds[buf][0][half][(wid + 8) * 512]);
            const ushort_t* gb = pb + (size_t)half * 128 * DIM_IN + t * 64;
            gload16(gb, &lds[buf][1][half][wid * 512]);
            gload16(gb + (size_t)64 * DIM_IN, &lds[buf][1][half][(wid + 8) * 512]);
        }
    };

    // consume buf: 8 segments of 8 MFMA, reads one segment ahead, no barriers.
    auto consume = [&](int buf) {
        const ushort_t* LA = &lds[buf][0][wr][0];
        const ushort_t* LB = &lds[buf][1][wc >> 1][0];
        const int bsub = (wc & 1) * 4;
        short8 aA[4], aB[4], bA[2][2], bB[2][2];

        auto rdA = [&](short8 (&dst)[4], int mhalf, int kk) {
#pragma unroll
            for (int m = 0; m < 4; ++m)
                dst[m] = *(const short8*)(LA + ((((mhalf * 4 + m) * 2) + kk) << 9) + loff);
        };
        auto rdB = [&](short8 (&dst)[2][2], int noff, int kk) {
#pragma unroll
            for (int n = 0; n < 2; ++n)
                dst[n][kk] = *(const short8*)(LB + ((((bsub + noff + n) * 2) + kk) << 9) + loff);
        };
        auto cluster = [&](short8 (&av)[4], short8 (&bv)[2][2], int kk, int mb, int nb) {
            __builtin_amdgcn_s_setprio(1);
#pragma unroll
            for (int m = 0; m < 4; ++m)
#pragma unroll
                for (int n = 0; n < 2; ++n)
                    acc[mb + m][nb + n] =
                        __builtin_amdgcn_mfma_f32_16x16x32_bf16(av[m], bv[n][kk], acc[mb + m][nb + n], 0, 0, 0);
            __builtin_amdgcn_s_setprio(0);
        };

        rdA(aA, 0, 0);                 // a03 k0
        rdB(bA, 0, 0);                 // b01 k0
        rdA(aB, 0, 1);                 // a03 k1
        rdB(bA, 0, 1);                 // b01 k1
        cluster(aA, bA, 0, 0, 0);      // seg0: m03 x n01 k0
        rdB(bB, 2, 0);                 // b23 k0
        cluster(aB, bA, 1, 0, 0);      // seg1: m03 x n01 k1
        rdB(bB, 2, 1);                 // b23 k1
        cluster(aA, bB, 0, 0, 2);      // seg2: m03 x n23 k0 (a03 k0 dies)
        rdA(aA, 1, 0);                 // a47 k0 (reuse aA)
        cluster(aB, bB, 1, 0, 2);      // seg3: m03 x n23 k1 (a03 k1 dies)
        rdA(aB, 1, 1);                 // a47 k1 (reuse aB)
        cluster(aA, bB, 0, 4, 2);      // seg4: m47 x n23 k0
        cluster(aB, bB, 1, 4, 2);      // seg5: m47 x n23 k1 (b23 dies)
        cluster(aA, bA, 0, 4, 0);      // seg6: m47 x n01 k0
        cluster(aB, bA, 1, 4, 0);      // seg7: m47 x n01 k1
    };

    // ---- prologue: stage tiles 0 and 1; wait tile 0 (8 of 16 outstanding)
    stage(0, 0);
    stage(1, 1);
    asm volatile("s_waitcnt vmcnt(8)" ::: "memory");
    __builtin_amdgcn_s_barrier();

    for (int t = 0; t < NT; ++t) {
        const int cur = t & 1;
        consume(cur);
        if (t == NT - 1) break;
        if (t + 2 < NT) {
            __builtin_amdgcn_s_barrier();            // all waves done reading cur
            stage(cur, t + 2);                       // burst: 8 gloads
            asm volatile("s_waitcnt vmcnt(8)" ::: "memory");  // t+1's 8 landed
        } else {
            asm volatile("s_waitcnt vmcnt(0)" ::: "memory");  // tail drain (t+1)
        }
        __builtin_amdgcn_s_barrier();                // t+1 resident chip-wide
    }

    // ---- epilogue: C/D layout col = lane&15, row = (lane>>4)*4 + reg
    const int ccol = lane & 15;
    const int crow = (lane >> 4) * 4;
#pragma unroll
    for (int n = 0; n < 4; ++n) {
        int gcol = bn * 256 + wc * 64 + n * 16 + ccol;
        float bv = bias[gcol];
#pragma unroll
        for (int m = 0; m < 8; ++m) {
            size_t grow = (size_t)(bm * 256 + wr * 128 + m * 16 + crow);
#pragma unroll
            for (int r = 0; r < 4; ++r)
                C[(grow + r) * DIM_OUT + gcol] = acc[m][n][r] + bv;
        }
    }
}

extern "C" void kernel_launch(void* const* d_in, const int* in_sizes, int n_in,
                              void* d_out, int out_size, void* d_ws, size_t ws_size,
                              hipStream_t stream) {
    const float* input = (const float*)d_in[0];
    const float* wq    = (const float*)d_in[1];
    const float* scale = (const float*)d_in[2];
    const float* bias  = (const float*)d_in[3];
    const float* U     = (const float*)d_in[4];
    const float* s     = (const float*)d_in[5];
    const float* V     = (const float*)d_in[6];
    float* out = (float*)d_out;

    ushort_t* Abf = (ushort_t*)d_ws;                       // 8192*4096*2 = 64 MB
    ushort_t* Wbf = Abf + (size_t)TOK * DIM_IN;            // 4096*4096*2 = 32 MB

    prep_input_k<<<(TOK * DIM_IN) / (256 * 8), 256, 0, stream>>>(input, Abf);
    prep_weight_k<<<(DIM_OUT / 128) * (DIM_IN / 128), 256, 0, stream>>>(wq, scale, U, s, V, Wbf);
    gemm_k<<<(TOK / 256) * (DIM_OUT / 256), 512, 0, stream>>>(Abf, Wbf, bias, out);
}

// Round 9
// 287.793 us; speedup vs baseline: 1.2605x; 1.1649x over previous
//
#include <hip/hip_runtime.h>
#include <stdint.h>

typedef unsigned short ushort_t;
typedef __attribute__((ext_vector_type(8))) short short8;
typedef __attribute__((ext_vector_type(4))) unsigned short ushort4_t;
typedef __attribute__((ext_vector_type(8))) unsigned short ushort8;
typedef __attribute__((ext_vector_type(4))) float f32x4;

#define TOK 8192
#define DIM_IN 4096
#define DIM_OUT 4096
#define RANK 64
#define NT (DIM_IN / 64)   // 64 K-tiles of BK=64

// fp32 -> bf16 round-to-nearest-even
__device__ __forceinline__ ushort_t f2bf(float f) {
    unsigned u = __float_as_uint(f);
    unsigned r = (u + 0x7fffu + ((u >> 16) & 1u)) >> 16;
    return (ushort_t)r;
}
__device__ __forceinline__ float bf2f(ushort_t u) {
    return __uint_as_float(((unsigned)u) << 16);
}

__device__ __forceinline__ void gload16(const void* g, void* l) {
    __builtin_amdgcn_global_load_lds(
        (const __attribute__((address_space(1))) unsigned int*)g,
        (__attribute__((address_space(3))) unsigned int*)l,
        16, 0, 0);
}

// ---------------- Kernel 1: input fp32 -> bf16 ----------------
__global__ __launch_bounds__(256) void prep_input_k(const float* __restrict__ in,
                                                    ushort_t* __restrict__ out) {
    size_t idx = (size_t)blockIdx.x * 256 + threadIdx.x;
    const float4* p = (const float4*)(in + idx * 8);
    float4 f0 = p[0], f1 = p[1];
    ushort8 o;
    o[0] = f2bf(f0.x); o[1] = f2bf(f0.y); o[2] = f2bf(f0.z); o[3] = f2bf(f0.w);
    o[4] = f2bf(f1.x); o[5] = f2bf(f1.y); o[6] = f2bf(f1.z); o[7] = f2bf(f1.w);
    *(ushort8*)(out + idx * 8) = o;
}

// ---------------- Kernel 2: W_eff = dequant(Wq,scale) + U*diag(s)*V^T -> bf16 ----------------
// MFMA version (r6 proven): svd part via bf16 16x16x32 MFMA per 128x128 tile,
// rounded to bf16 through LDS, then coalesced merge with dequantized wq.
__global__ __launch_bounds__(256) void prep_weight_k(const float* __restrict__ wq,
                                                     const float* __restrict__ scale,
                                                     const float* __restrict__ U,
                                                     const float* __restrict__ s,
                                                     const float* __restrict__ V,
                                                     ushort_t* __restrict__ Wb) {
    __shared__ ushort_t sm[18432];   // 36 KiB
    const int tid = threadIdx.x;
    const int wv = tid >> 6;
    const int lane = tid & 63;
    const int ob = blockIdx.x >> 5;
    const int kb = blockIdx.x & 31;

    // ---- stage U' = U*s and V' = V as bf16, swizzled (byte ^= (row&7)<<4)
    char* smb = (char*)sm;
#pragma unroll
    for (int j = 0; j < 8; ++j) {
        int idx = j * 256 + tid;          // 0..2047 float4 slots
        int row = idx >> 4;               // 0..127
        int c4 = idx & 15;                // float4 col index (cols c4*4)
        float4 sv = *(const float4*)&s[c4 * 4];
        float4 u = *(const float4*)&U[(size_t)(ob * 128 + row) * RANK + c4 * 4];
        ushort4_t up;
        up[0] = f2bf(u.x * sv.x); up[1] = f2bf(u.y * sv.y);
        up[2] = f2bf(u.z * sv.z); up[3] = f2bf(u.w * sv.w);
        int wbyte = row * 128 + ((c4 * 8) ^ ((row & 7) << 4));
        *(ushort4_t*)(smb + wbyte) = up;
        float4 v = *(const float4*)&V[(size_t)(kb * 128 + row) * RANK + c4 * 4];
        ushort4_t vp;
        vp[0] = f2bf(v.x); vp[1] = f2bf(v.y); vp[2] = f2bf(v.z); vp[3] = f2bf(v.w);
        *(ushort4_t*)(smb + 16384 + wbyte) = vp;
    }
    __syncthreads();

    // ---- MFMA: wave wv -> out quadrant (wr = wv>>1)*64 rows, (wc = wv&1)*64 cols
    const int wr = wv >> 1, wc = wv & 1;
    f32x4 acc[4][4] = {};
    {
        short8 a[4], b[4];
#pragma unroll
        for (int kk = 0; kk < 2; ++kk) {
#pragma unroll
            for (int f = 0; f < 4; ++f) {
                int r = wr * 64 + f * 16 + (lane & 15);
                int kbyte = ((lane >> 4) * 16 + kk * 64) ^ ((r & 7) << 4);
                a[f] = *(const short8*)(smb + r * 128 + kbyte);
                int r2 = wc * 64 + f * 16 + (lane & 15);
                int kbyte2 = ((lane >> 4) * 16 + kk * 64) ^ ((r2 & 7) << 4);
                b[f] = *(const short8*)(smb + 16384 + r2 * 128 + kbyte2);
            }
#pragma unroll
            for (int fm = 0; fm < 4; ++fm)
#pragma unroll
                for (int fn = 0; fn < 4; ++fn)
                    acc[fm][fn] = __builtin_amdgcn_mfma_f32_16x16x32_bf16(
                        a[fm], b[fn], acc[fm][fn], 0, 0, 0);
        }
    }
    __syncthreads();   // all MFMA reads of U'/V' done before overwrite

    // ---- spill svd (bf16) to LDS as [128][136] ushort
#pragma unroll
    for (int fm = 0; fm < 4; ++fm)
#pragma unroll
        for (int fn = 0; fn < 4; ++fn) {
            int row0 = wr * 64 + fm * 16 + (lane >> 4) * 4;
            int col = wc * 64 + fn * 16 + (lane & 15);
#pragma unroll
            for (int r = 0; r < 4; ++r)
                sm[(row0 + r) * 136 + col] = f2bf(acc[fm][fn][r]);
        }
    __syncthreads();

    // ---- merge: out = wq*scale + svd, coalesced ushort8 stores
    const int ty = tid >> 4, tx = tid & 15;
#pragma unroll
    for (int i = 0; i < 8; ++i) {
        int ol = ty * 8 + i;
        int o = ob * 128 + ol;
        int k0 = kb * 128 + tx * 8;
        float sc = scale[(size_t)o * (DIM_IN / 32) + (k0 >> 5)];
        float4 q0 = *(const float4*)&wq[(size_t)o * DIM_IN + k0];
        float4 q1 = *(const float4*)&wq[(size_t)o * DIM_IN + k0 + 4];
        ushort8 sv8 = *(const ushort8*)&sm[ol * 136 + tx * 8];
        ushort8 w;
        w[0] = f2bf(q0.x * sc + bf2f(sv8[0]));
        w[1] = f2bf(q0.y * sc + bf2f(sv8[1]));
        w[2] = f2bf(q0.z * sc + bf2f(sv8[2]));
        w[3] = f2bf(q0.w * sc + bf2f(sv8[3]));
        w[4] = f2bf(q1.x * sc + bf2f(sv8[4]));
        w[5] = f2bf(q1.y * sc + bf2f(sv8[5]));
        w[6] = f2bf(q1.z * sc + bf2f(sv8[6]));
        w[7] = f2bf(q1.w * sc + bf2f(sv8[7]));
        *(ushort8*)&Wb[(size_t)o * DIM_IN + k0] = w;
    }
}

// ---------------- Kernel 3: 256^2 GEMM, C = A @ B^T + bias (r4 proven schedule) ----------------
// 512 threads (8 waves, 2M x 4N), BK=64, st_16x32-swizzled LDS, counted vmcnt(6).
// Tile = 8 segments of 8 MFMA; reads issued one segment ahead. Mid-phase barriers
// at B-drain / A-drain stagger the waves' LDS read bursts against MFMA clusters
// (removing them floods the LDS pipe in lockstep -- r8 regression). 235 us, 53% MfmaUtil.
__global__ __launch_bounds__(512, 2) void gemm_k(const ushort_t* __restrict__ A,
                                                 const ushort_t* __restrict__ B,
                                                 const float* __restrict__ bias,
                                                 float* __restrict__ C) {
    __shared__ ushort_t lds[2][2][2][8192];

    const int tid = threadIdx.x;
    const int wid = tid >> 6;
    const int lane = tid & 63;

    // XCD-aware bijective swizzle: 512 blocks, 8 XCDs, 64 per XCD
    int bid = blockIdx.x;
    int swz = (bid & 7) * 64 + (bid >> 3);
    const int bm = swz >> 4;   // 32 M-tiles
    const int bn = swz & 15;   // 16 N-tiles

    const int wr = wid >> 2;   // 0..1 (M)
    const int wc = wid & 3;    // 0..3 (N)

    // --- staging: wave wid fills subtiles {wid, wid+8} of each 128x64 half-tile.
    const int lane2 = lane ^ (((lane >> 5) & 1) << 1);
    const int srow = (wid >> 1) * 16 + (lane2 >> 2);
    const int scol = (wid & 1) * 32 + (lane2 & 3) * 8;
    const ushort_t* pa = A + (size_t)(bm * 256 + srow) * DIM_IN + scol;
    const ushort_t* pb = B + (size_t)(bn * 256 + srow) * DIM_IN + scol;

    // --- swizzled per-lane ds_read offset (element units)
    const int loff = ((((lane & 15) * 64 + (lane >> 4) * 16) ^ (((lane >> 3) & 1) << 5)) >> 1);

    f32x4 acc[8][4] = {};

    auto stageA = [&](int buf, int half, int t) {
        const ushort_t* g = pa + (size_t)half * 128 * DIM_IN + t * 64;
        gload16(g, &lds[buf][0][half][wid * 512]);
        gload16(g + (size_t)64 * DIM_IN, &lds[buf][0][half][(wid + 8) * 512]);
    };
    auto stageB = [&](int buf, int half, int t) {
        const ushort_t* g = pb + (size_t)half * 128 * DIM_IN + t * 64;
        gload16(g, &lds[buf][1][half][wid * 512]);
        gload16(g + (size_t)64 * DIM_IN, &lds[buf][1][half][(wid + 8) * 512]);
    };

    // mode: 2 = steady state; 1 = t=NT-2 (only P0 stage, vmcnt(0)); 0 = last tile
    auto tile_step = [&](int buf, int t, int mode) {
        const ushort_t* LA = &lds[buf][0][wr][0];
        const ushort_t* LB = &lds[buf][1][wc >> 1][0];
        const int bsub = (wc & 1) * 4;
        short8 aA[4], aB[4], bA[2][2], bB[2][2];

        auto rdA = [&](short8 (&dst)[4], int mhalf, int kk) {
#pragma unroll
            for (int m = 0; m < 4; ++m)
                dst[m] = *(const short8*)(LA + ((((mhalf * 4 + m) * 2) + kk) << 9) + loff);
        };
        auto rdB = [&](short8 (&dst)[2][2], int noff, int kk) {
#pragma unroll
            for (int n = 0; n < 2; ++n)
                dst[n][kk] = *(const short8*)(LB + ((((bsub + noff + n) * 2) + kk) << 9) + loff);
        };
        auto cluster = [&](short8 (&av)[4], short8 (&bv)[2][2], int kk, int mb, int nb) {
            __builtin_amdgcn_s_setprio(1);
#pragma unroll
            for (int m = 0; m < 4; ++m)
#pragma unroll
                for (int n = 0; n < 2; ++n)
                    acc[mb + m][nb + n] =
                        __builtin_amdgcn_mfma_f32_16x16x32_bf16(av[m], bv[n][kk], acc[mb + m][nb + n], 0, 0, 0);
            __builtin_amdgcn_s_setprio(0);
        };

        // ---- PH0 (m0-3 x n0-1): seg0+seg1 reads up front (tile-boundary exposure)
        rdA(aA, 0, 0);                 // seg0: a03 k0  [4]
        rdB(bA, 0, 0);                 // seg0: b01 k0  [2]
        rdA(aB, 0, 1);                 // seg1: a03 k1  [4]
        rdB(bA, 0, 1);                 // seg1: b01 k1  [2]
        if (mode >= 1) stageA(buf ^ 1, 1, t + 1);
        cluster(aA, bA, 0, 0, 0);      // seg0
        rdB(bB, 2, 0);                 // seg2 ops: b23 k0 [2]
        cluster(aB, bA, 1, 0, 0);      // seg1

        // ---- PH1 (m0-3 x n2-3)
        rdB(bB, 2, 1);                 // seg3 ops: b23 k1 [2]
        cluster(aA, bB, 0, 0, 2);      // seg2 (last use of a03 k0)
        rdA(aA, 1, 0);                 // seg4 ops: a47 k0 -> reuse aA (WAR after seg2)
        cluster(aB, bB, 1, 0, 2);      // seg3 (last use of a03 k1)
        __builtin_amdgcn_s_barrier();  // P1-end: all waves' B(t) reads complete

        // ---- PH2 (m4-7 x n2-3): B region of buf now safe to restage
        rdA(aB, 1, 1);                 // seg5 ops: a47 k1 -> reuse aB
        if (mode == 2) { stageB(buf, 0, t + 2); stageB(buf, 1, t + 2); }
        cluster(aA, bB, 0, 4, 2);      // seg4
        cluster(aB, bB, 1, 4, 2);      // seg5 (last use of b23)
        __builtin_amdgcn_s_barrier();  // P2-end: all waves' A(t) reads complete

        // ---- PH3 (m4-7 x n0-1): no reads; A region safe to restage
        if (mode == 2) stageA(buf, 0, t + 2);
        cluster(aA, bA, 0, 4, 0);      // seg6
        cluster(aB, bA, 1, 4, 0);      // seg7
        if (mode == 2)
            asm volatile("s_waitcnt vmcnt(6)" ::: "memory");   // tile t+1 fully landed
        else if (mode == 1)
            asm volatile("s_waitcnt vmcnt(0)" ::: "memory");   // tail drain
        if (mode >= 1) __builtin_amdgcn_s_barrier();           // tile-end
    };

    // ---- prologue: tile0 (4 halves) + tile1 (B0,B1,A0); A1(t1) staged at t0.P0
    stageA(0, 0, 0); stageA(0, 1, 0); stageB(0, 0, 0); stageB(0, 1, 0);
    stageB(1, 0, 1); stageB(1, 1, 1); stageA(1, 0, 1);
    asm volatile("s_waitcnt vmcnt(6)" ::: "memory");           // tile0 landed
    __builtin_amdgcn_s_barrier();

    for (int t = 0; t < NT - 2; t += 2) {
        tile_step(0, t, 2);
        tile_step(1, t + 1, 2);
    }
    tile_step(0, NT - 2, 1);
    tile_step(1, NT - 1, 0);

    // ---- epilogue: C/D layout col = lane&15, row = (lane>>4)*4 + reg
    const int ccol = lane & 15;
    const int crow = (lane >> 4) * 4;
#pragma unroll
    for (int n = 0; n < 4; ++n) {
        int gcol = bn * 256 + wc * 64 + n * 16 + ccol;
        float bv = bias[gcol];
#pragma unroll
        for (int m = 0; m < 8; ++m) {
            size_t grow = (size_t)(bm * 256 + wr * 128 + m * 16 + crow);
#pragma unroll
            for (int r = 0; r < 4; ++r)
                C[(grow + r) * DIM_OUT + gcol] = acc[m][n][r] + bv;
        }
    }
}

extern "C" void kernel_launch(void* const* d_in, const int* in_sizes, int n_in,
                              void* d_out, int out_size, void* d_ws, size_t ws_size,
                              hipStream_t stream) {
    const float* input = (const float*)d_in[0];
    const float* wq    = (const float*)d_in[1];
    const float* scale = (const float*)d_in[2];
    const float* bias  = (const float*)d_in[3];
    const float* U     = (const float*)d_in[4];
    const float* s     = (const float*)d_in[5];
    const float* V     = (const float*)d_in[6];
    float* out = (float*)d_out;

    ushort_t* Abf = (ushort_t*)d_ws;                       // 8192*4096*2 = 64 MB
    ushort_t* Wbf = Abf + (size_t)TOK * DIM_IN;            // 4096*4096*2 = 32 MB

    prep_input_k<<<(TOK * DIM_IN) / (256 * 8), 256, 0, stream>>>(input, Abf);
    prep_weight_k<<<(DIM_OUT / 128) * (DIM_IN / 128), 256, 0, stream>>>(wq, scale, U, s, V, Wbf);
    gemm_k<<<(TOK / 256) * (DIM_OUT / 256), 512, 0, stream>>>(Abf, Wbf, bias, out);
}

// Round 11
// 280.622 us; speedup vs baseline: 1.2927x; 1.0256x over previous
//
#include <hip/hip_runtime.h>
#include <stdint.h>

typedef unsigned short ushort_t;
typedef __attribute__((ext_vector_type(8))) short short8;
typedef __attribute__((ext_vector_type(4))) unsigned short ushort4_t;
typedef __attribute__((ext_vector_type(8))) unsigned short ushort8;
typedef __attribute__((ext_vector_type(4))) float f32x4;

#define TOK 8192
#define DIM_IN 4096
#define DIM_OUT 4096
#define RANK 64
#define NT (DIM_IN / 64)                      // 64 K-tiles of BK=64
#define NBLK_IN ((TOK * DIM_IN) / (256 * 8))  // 16384 input-cast blocks
#define NBLK_W 1024                           // weight-build blocks

// fp32 -> bf16 round-to-nearest-even
__device__ __forceinline__ ushort_t f2bf(float f) {
    unsigned u = __float_as_uint(f);
    unsigned r = (u + 0x7fffu + ((u >> 16) & 1u)) >> 16;
    return (ushort_t)r;
}
__device__ __forceinline__ float bf2f(ushort_t u) {
    return __uint_as_float(((unsigned)u) << 16);
}

__device__ __forceinline__ void gload16(const void* g, void* l) {
    __builtin_amdgcn_global_load_lds(
        (const __attribute__((address_space(1))) unsigned int*)g,
        (__attribute__((address_space(3))) unsigned int*)l,
        16, 0, 0);
}

// ---------------- Kernel 1: fused prep ----------------
// blocks [0, NBLK_IN): input fp32 -> bf16 cast (streaming).
// blocks [NBLK_IN, NBLK_IN+NBLK_W): W_eff = dequant(Wq,scale) + U*diag(s)*V^T -> bf16
//   (r6-proven MFMA version: svd part via bf16 16x16x32 MFMA per 128x128 tile,
//    rounded to bf16 through LDS, then coalesced merge with dequantized wq).
__global__ __launch_bounds__(256) void prep_k(const float* __restrict__ in,
                                              ushort_t* __restrict__ Abf,
                                              const float* __restrict__ wq,
                                              const float* __restrict__ scale,
                                              const float* __restrict__ U,
                                              const float* __restrict__ s,
                                              const float* __restrict__ V,
                                              ushort_t* __restrict__ Wb) {
    __shared__ ushort_t sm[18432];   // 36 KiB (weight branch only)
    const int tid = threadIdx.x;

    if (blockIdx.x < NBLK_IN) {
        // ---- input cast: 8 elems/thread, ushort8 stores
        size_t idx = (size_t)blockIdx.x * 256 + tid;
        const float4* p = (const float4*)(in + idx * 8);
        float4 f0 = p[0], f1 = p[1];
        ushort8 o;
        o[0] = f2bf(f0.x); o[1] = f2bf(f0.y); o[2] = f2bf(f0.z); o[3] = f2bf(f0.w);
        o[4] = f2bf(f1.x); o[5] = f2bf(f1.y); o[6] = f2bf(f1.z); o[7] = f2bf(f1.w);
        *(ushort8*)(Abf + idx * 8) = o;
        return;
    }

    const int wbid = blockIdx.x - NBLK_IN;
    const int wv = tid >> 6;
    const int lane = tid & 63;
    const int ob = wbid >> 5;
    const int kb = wbid & 31;

    // ---- stage U' = U*s and V' = V as bf16, swizzled (byte ^= (row&7)<<4)
    char* smb = (char*)sm;
#pragma unroll
    for (int j = 0; j < 8; ++j) {
        int idx = j * 256 + tid;          // 0..2047 float4 slots
        int row = idx >> 4;               // 0..127
        int c4 = idx & 15;                // float4 col index (cols c4*4)
        float4 sv = *(const float4*)&s[c4 * 4];
        float4 u = *(const float4*)&U[(size_t)(ob * 128 + row) * RANK + c4 * 4];
        ushort4_t up;
        up[0] = f2bf(u.x * sv.x); up[1] = f2bf(u.y * sv.y);
        up[2] = f2bf(u.z * sv.z); up[3] = f2bf(u.w * sv.w);
        int wbyte = row * 128 + ((c4 * 8) ^ ((row & 7) << 4));
        *(ushort4_t*)(smb + wbyte) = up;
        float4 v = *(const float4*)&V[(size_t)(kb * 128 + row) * RANK + c4 * 4];
        ushort4_t vp;
        vp[0] = f2bf(v.x); vp[1] = f2bf(v.y); vp[2] = f2bf(v.z); vp[3] = f2bf(v.w);
        *(ushort4_t*)(smb + 16384 + wbyte) = vp;
    }
    __syncthreads();

    // ---- MFMA: wave wv -> out quadrant (wr = wv>>1)*64 rows, (wc = wv&1)*64 cols
    const int wr = wv >> 1, wc = wv & 1;
    f32x4 acc[4][4] = {};
    {
        short8 a[4], b[4];
#pragma unroll
        for (int kk = 0; kk < 2; ++kk) {
#pragma unroll
            for (int f = 0; f < 4; ++f) {
                int r = wr * 64 + f * 16 + (lane & 15);
                int kbyte = ((lane >> 4) * 16 + kk * 64) ^ ((r & 7) << 4);
                a[f] = *(const short8*)(smb + r * 128 + kbyte);
                int r2 = wc * 64 + f * 16 + (lane & 15);
                int kbyte2 = ((lane >> 4) * 16 + kk * 64) ^ ((r2 & 7) << 4);
                b[f] = *(const short8*)(smb + 16384 + r2 * 128 + kbyte2);
            }
#pragma unroll
            for (int fm = 0; fm < 4; ++fm)
#pragma unroll
                for (int fn = 0; fn < 4; ++fn)
                    acc[fm][fn] = __builtin_amdgcn_mfma_f32_16x16x32_bf16(
                        a[fm], b[fn], acc[fm][fn], 0, 0, 0);
        }
    }
    __syncthreads();   // all MFMA reads of U'/V' done before overwrite

    // ---- spill svd (bf16) to LDS as [128][136] ushort
    // C/D: col = lane&15 (k/fn axis), row = (lane>>4)*4 + reg (o/fm axis)
#pragma unroll
    for (int fm = 0; fm < 4; ++fm)
#pragma unroll
        for (int fn = 0; fn < 4; ++fn) {
            int row0 = wr * 64 + fm * 16 + (lane >> 4) * 4;
            int col = wc * 64 + fn * 16 + (lane & 15);
#pragma unroll
            for (int r = 0; r < 4; ++r)
                sm[(row0 + r) * 136 + col] = f2bf(acc[fm][fn][r]);
        }
    __syncthreads();

    // ---- merge: out = wq*scale + svd, coalesced ushort8 stores
    const int ty = tid >> 4, tx = tid & 15;
#pragma unroll
    for (int i = 0; i < 8; ++i) {
        int ol = ty * 8 + i;
        int o = ob * 128 + ol;
        int k0 = kb * 128 + tx * 8;
        float sc = scale[(size_t)o * (DIM_IN / 32) + (k0 >> 5)];
        float4 q0 = *(const float4*)&wq[(size_t)o * DIM_IN + k0];
        float4 q1 = *(const float4*)&wq[(size_t)o * DIM_IN + k0 + 4];
        ushort8 sv8 = *(const ushort8*)&sm[ol * 136 + tx * 8];
        ushort8 w;
        w[0] = f2bf(q0.x * sc + bf2f(sv8[0]));
        w[1] = f2bf(q0.y * sc + bf2f(sv8[1]));
        w[2] = f2bf(q0.z * sc + bf2f(sv8[2]));
        w[3] = f2bf(q0.w * sc + bf2f(sv8[3]));
        w[4] = f2bf(q1.x * sc + bf2f(sv8[4]));
        w[5] = f2bf(q1.y * sc + bf2f(sv8[5]));
        w[6] = f2bf(q1.z * sc + bf2f(sv8[6]));
        w[7] = f2bf(q1.w * sc + bf2f(sv8[7]));
        *(ushort8*)&Wb[(size_t)o * DIM_IN + k0] = w;
    }
}

// ---------------- Kernel 2: 256^2 GEMM, C = A @ B^T + bias (r4 proven schedule) ----------------
// 512 threads (8 waves, 2M x 4N), BK=64, st_16x32-swizzled LDS, counted vmcnt(6).
// Tile = 8 segments of 8 MFMA; reads issued one segment ahead. Mid-phase barriers
// at B-drain / A-drain stagger the waves' LDS read bursts against MFMA clusters
// (removing them floods the LDS pipe in lockstep -- r8 regression). 235 us, 53% MfmaUtil.
__global__ __launch_bounds__(512, 2) void gemm_k(const ushort_t* __restrict__ A,
                                                 const ushort_t* __restrict__ B,
                                                 const float* __restrict__ bias,
                                                 float* __restrict__ C) {
    __shared__ ushort_t lds[2][2][2][8192];

    const int tid = threadIdx.x;
    const int wid = tid >> 6;
    const int lane = tid & 63;

    // XCD-aware bijective swizzle: 512 blocks, 8 XCDs, 64 per XCD
    int bid = blockIdx.x;
    int swz = (bid & 7) * 64 + (bid >> 3);
    const int bm = swz >> 4;   // 32 M-tiles
    const int bn = swz & 15;   // 16 N-tiles

    const int wr = wid >> 2;   // 0..1 (M)
    const int wc = wid & 3;    // 0..3 (N)

    // --- staging: wave wid fills subtiles {wid, wid+8} of each 128x64 half-tile.
    const int lane2 = lane ^ (((lane >> 5) & 1) << 1);
    const int srow = (wid >> 1) * 16 + (lane2 >> 2);
    const int scol = (wid & 1) * 32 + (lane2 & 3) * 8;
    const ushort_t* pa = A + (size_t)(bm * 256 + srow) * DIM_IN + scol;
    const ushort_t* pb = B + (size_t)(bn * 256 + srow) * DIM_IN + scol;

    // --- swizzled per-lane ds_read offset (element units)
    const int loff = ((((lane & 15) * 64 + (lane >> 4) * 16) ^ (((lane >> 3) & 1) << 5)) >> 1);

    f32x4 acc[8][4] = {};

    auto stageA = [&](int buf, int half, int t) {
        const ushort_t* g = pa + (size_t)half * 128 * DIM_IN + t * 64;
        gload16(g, &lds[buf][0][half][wid * 512]);
        gload16(g + (size_t)64 * DIM_IN, &lds[buf][0][half][(wid + 8) * 512]);
    };
    auto stageB = [&](int buf, int half, int t) {
        const ushort_t* g = pb + (size_t)half * 128 * DIM_IN + t * 64;
        gload16(g, &lds[buf][1][half][wid * 512]);
        gload16(g + (size_t)64 * DIM_IN, &lds[buf][1][half][(wid + 8) * 512]);
    };

    // mode: 2 = steady state; 1 = t=NT-2 (only P0 stage, vmcnt(0)); 0 = last tile
    auto tile_step = [&](int buf, int t, int mode) {
        const ushort_t* LA = &lds[buf][0][wr][0];
        const ushort_t* LB = &lds[buf][1][wc >> 1][0];
        const int bsub = (wc & 1) * 4;
        short8 aA[4], aB[4], bA[2][2], bB[2][2];

        auto rdA = [&](short8 (&dst)[4], int mhalf, int kk) {
#pragma unroll
            for (int m = 0; m < 4; ++m)
                dst[m] = *(const short8*)(LA + ((((mhalf * 4 + m) * 2) + kk) << 9) + loff);
        };
        auto rdB = [&](short8 (&dst)[2][2], int noff, int kk) {
#pragma unroll
            for (int n = 0; n < 2; ++n)
                dst[n][kk] = *(const short8*)(LB + ((((bsub + noff + n) * 2) + kk) << 9) + loff);
        };
        auto cluster = [&](short8 (&av)[4], short8 (&bv)[2][2], int kk, int mb, int nb) {
            __builtin_amdgcn_s_setprio(1);
#pragma unroll
            for (int m = 0; m < 4; ++m)
#pragma unroll
                for (int n = 0; n < 2; ++n)
                    acc[mb + m][nb + n] =
                        __builtin_amdgcn_mfma_f32_16x16x32_bf16(av[m], bv[n][kk], acc[mb + m][nb + n], 0, 0, 0);
            __builtin_amdgcn_s_setprio(0);
        };

        // ---- PH0 (m0-3 x n0-1): seg0+seg1 reads up front (tile-boundary exposure)
        rdA(aA, 0, 0);                 // seg0: a03 k0  [4]
        rdB(bA, 0, 0);                 // seg0: b01 k0  [2]
        rdA(aB, 0, 1);                 // seg1: a03 k1  [4]
        rdB(bA, 0, 1);                 // seg1: b01 k1  [2]
        if (mode >= 1) stageA(buf ^ 1, 1, t + 1);
        cluster(aA, bA, 0, 0, 0);      // seg0
        rdB(bB, 2, 0);                 // seg2 ops: b23 k0 [2]
        cluster(aB, bA, 1, 0, 0);      // seg1

        // ---- PH1 (m0-3 x n2-3)
        rdB(bB, 2, 1);                 // seg3 ops: b23 k1 [2]
        cluster(aA, bB, 0, 0, 2);      // seg2 (last use of a03 k0)
        rdA(aA, 1, 0);                 // seg4 ops: a47 k0 -> reuse aA (WAR after seg2)
        cluster(aB, bB, 1, 0, 2);      // seg3 (last use of a03 k1)
        __builtin_amdgcn_s_barrier();  // P1-end: all waves' B(t) reads complete

        // ---- PH2 (m4-7 x n2-3): B region of buf now safe to restage
        rdA(aB, 1, 1);                 // seg5 ops: a47 k1 -> reuse aB
        if (mode == 2) { stageB(buf, 0, t + 2); stageB(buf, 1, t + 2); }
        cluster(aA, bB, 0, 4, 2);      // seg4
        cluster(aB, bB, 1, 4, 2);      // seg5 (last use of b23)
        __builtin_amdgcn_s_barrier();  // P2-end: all waves' A(t) reads complete

        // ---- PH3 (m4-7 x n0-1): no reads; A region safe to restage
        if (mode == 2) stageA(buf, 0, t + 2);
        cluster(aA, bA, 0, 4, 0);      // seg6
        cluster(aB, bA, 1, 4, 0);      // seg7
        if (mode == 2)
            asm volatile("s_waitcnt vmcnt(6)" ::: "memory");   // tile t+1 fully landed
        else if (mode == 1)
            asm volatile("s_waitcnt vmcnt(0)" ::: "memory");   // tail drain
        if (mode >= 1) __builtin_amdgcn_s_barrier();           // tile-end
    };

    // ---- prologue: tile0 (4 halves) + tile1 (B0,B1,A0); A1(t1) staged at t0.P0
    stageA(0, 0, 0); stageA(0, 1, 0); stageB(0, 0, 0); stageB(0, 1, 0);
    stageB(1, 0, 1); stageB(1, 1, 1); stageA(1, 0, 1);
    asm volatile("s_waitcnt vmcnt(6)" ::: "memory");           // tile0 landed
    __builtin_amdgcn_s_barrier();

    for (int t = 0; t < NT - 2; t += 2) {
        tile_step(0, t, 2);
        tile_step(1, t + 1, 2);
    }
    tile_step(0, NT - 2, 1);
    tile_step(1, NT - 1, 0);

    // ---- epilogue: C/D layout col = lane&15, row = (lane>>4)*4 + reg
    const int ccol = lane & 15;
    const int crow = (lane >> 4) * 4;
#pragma unroll
    for (int n = 0; n < 4; ++n) {
        int gcol = bn * 256 + wc * 64 + n * 16 + ccol;
        float bv = bias[gcol];
#pragma unroll
        for (int m = 0; m < 8; ++m) {
            size_t grow = (size_t)(bm * 256 + wr * 128 + m * 16 + crow);
#pragma unroll
            for (int r = 0; r < 4; ++r)
                C[(grow + r) * DIM_OUT + gcol] = acc[m][n][r] + bv;
        }
    }
}

extern "C" void kernel_launch(void* const* d_in, const int* in_sizes, int n_in,
                              void* d_out, int out_size, void* d_ws, size_t ws_size,
                              hipStream_t stream) {
    const float* input = (const float*)d_in[0];
    const float* wq    = (const float*)d_in[1];
    const float* scale = (const float*)d_in[2];
    const float* bias  = (const float*)d_in[3];
    const float* U     = (const float*)d_in[4];
    const float* s     = (const float*)d_in[5];
    const float* V     = (const float*)d_in[6];
    float* out = (float*)d_out;

    ushort_t* Abf = (ushort_t*)d_ws;                       // 8192*4096*2 = 64 MB
    ushort_t* Wbf = Abf + (size_t)TOK * DIM_IN;            // 4096*4096*2 = 32 MB

    prep_k<<<NBLK_IN + NBLK_W, 256, 0, stream>>>(input, Abf, wq, scale, U, s, V, Wbf);
    gemm_k<<<(TOK / 256) * (DIM_OUT / 256), 512, 0, stream>>>(Abf, Wbf, bias, out);
}